// Round 1
// baseline (1949.269 us; speedup 1.0000x reference)
//
#include <hip/hip_runtime.h>
#include <hip/hip_bf16.h>
#include <cmath>

#define SLOPE 0.2f

// ---------------------------------------------------------------- preprocessing

__global__ __launch_bounds__(256) void count_deg_kernel(
    const int* __restrict__ dstv, const float* __restrict__ eattr,
    int* __restrict__ deg, float* __restrict__ loop_sum, int E)
{
    int e = blockIdx.x * 256 + threadIdx.x;
    if (e >= E) return;
    int d = dstv[e];
    atomicAdd(&deg[d], 1);
    float4 ea = *(const float4*)(eattr + (size_t)e * 4);
    atomicAdd(&loop_sum[(size_t)d * 4 + 0], ea.x);
    atomicAdd(&loop_sum[(size_t)d * 4 + 1], ea.y);
    atomicAdd(&loop_sum[(size_t)d * 4 + 2], ea.z);
    atomicAdd(&loop_sum[(size_t)d * 4 + 3], ea.w);
}

// exclusive prefix over (deg[i]+1): rowptr[0]=0, rowptr[i+1]=sum_{j<=i}(deg[j]+1)
__global__ void scan_kernel(const int* __restrict__ deg, int* __restrict__ rowptr, int N)
{
    __shared__ int swsum[16];
    __shared__ int sbase[16];
    __shared__ int stotal;
    __shared__ int scarry;
    int t = threadIdx.x, lane = t & 63, w = t >> 6;
    if (t == 0) { scarry = 0; rowptr[0] = 0; }
    __syncthreads();
    for (int base = 0; base < N; base += 1024) {
        int i = base + t;
        int v = (i < N) ? (deg[i] + 1) : 0;
        #pragma unroll
        for (int off = 1; off < 64; off <<= 1) {
            int u = __shfl_up(v, off);
            if (lane >= off) v += u;
        }
        if (lane == 63) swsum[w] = v;
        __syncthreads();
        if (w == 0 && lane < 16) {
            int xv = swsum[lane];
            int orig = xv;
            #pragma unroll
            for (int off = 1; off < 16; off <<= 1) {
                int u = __shfl_up(xv, off);
                if (lane >= off) xv += u;
            }
            sbase[lane] = xv - orig;
            if (lane == 15) stotal = xv;
        }
        __syncthreads();
        if (i < N) rowptr[i + 1] = scarry + sbase[w] + v;
        __syncthreads();
        if (t == 0) scarry += stotal;
        __syncthreads();
    }
}

__global__ __launch_bounds__(256) void fill_csr_kernel(
    const int* __restrict__ srcv, const int* __restrict__ dstv,
    const int* __restrict__ rowptr, int* __restrict__ fill,
    int* __restrict__ col, int* __restrict__ eid, int E)
{
    int e = blockIdx.x * 256 + threadIdx.x;
    if (e >= E) return;
    int d = dstv[e];
    int pos = rowptr[d] + atomicAdd(&fill[d], 1);
    col[pos] = srcv[e];
    eid[pos] = e;
}

__global__ __launch_bounds__(256) void selfloop_kernel(
    const int* __restrict__ rowptr, const int* __restrict__ deg,
    int* __restrict__ col, int* __restrict__ eid,
    float* __restrict__ loopat, int N, int E)
{
    int n = blockIdx.x * 256 + threadIdx.x;
    if (n >= N) return;
    int pos = rowptr[n + 1] - 1;       // slot rowptr[n]+deg[n]
    col[pos] = n;
    eid[pos] = E + n;
    float inv = 1.0f / fmaxf((float)deg[n], 1.0f);
    loopat[(size_t)n * 4 + 0] *= inv;
    loopat[(size_t)n * 4 + 1] *= inv;
    loopat[(size_t)n * 4 + 2] *= inv;
    loopat[(size_t)n * 4 + 3] *= inv;
}

// ---------------------------------------------------------------- fused xl/xr GEMM
// XL = H @ Wl, XR = H @ Wr.  H:[nrows,128], W:[128,128].
// block: 256 threads, 128-row tile, 256 virtual cols (=XL|XR), k-chunk 32.
__global__ __launch_bounds__(256, 2) void gemm_xlxr_kernel(
    const float* __restrict__ H, const float* __restrict__ Wl, const float* __restrict__ Wr,
    float* __restrict__ XL, float* __restrict__ XR, int nrows)
{
    __shared__ float sH[128][32];
    __shared__ float sW[32][256];
    int t = threadIdx.x;
    int r0 = blockIdx.x * 128;
    int rg = t >> 4;      // 16 row groups * 8 rows
    int cg = t & 15;      // 16 col groups * 16 cols
    float acc[8][16];
    #pragma unroll
    for (int i = 0; i < 8; ++i)
        #pragma unroll
        for (int j = 0; j < 16; ++j) acc[i][j] = 0.f;

    for (int kc = 0; kc < 128; kc += 32) {
        __syncthreads();
        #pragma unroll
        for (int li = 0; li < 4; ++li) {
            int idx = t + li * 256;           // 1024 = 128 rows * 8 float4
            int r = idx >> 3, k4 = idx & 7;
            int gr = r0 + r;
            float4 hv = make_float4(0.f, 0.f, 0.f, 0.f);
            if (gr < nrows) hv = *(const float4*)&H[(size_t)gr * 128 + kc + k4 * 4];
            *(float4*)&sH[r][k4 * 4] = hv;
        }
        #pragma unroll
        for (int li = 0; li < 4; ++li) {
            int idx = t + li * 256;           // 1024 = 32 rows * 32 float4 (per half)
            int k = idx >> 5, c4 = idx & 31;
            *(float4*)&sW[k][c4 * 4]       = *(const float4*)&Wl[(size_t)(kc + k) * 128 + c4 * 4];
            *(float4*)&sW[k][128 + c4 * 4] = *(const float4*)&Wr[(size_t)(kc + k) * 128 + c4 * 4];
        }
        __syncthreads();
        #pragma unroll
        for (int k4 = 0; k4 < 8; ++k4) {
            float4 h[8];
            #pragma unroll
            for (int i = 0; i < 8; ++i) h[i] = *(const float4*)&sH[rg * 8 + i][k4 * 4];
            #pragma unroll
            for (int dk = 0; dk < 4; ++dk) {
                float4 wv[4];
                #pragma unroll
                for (int j4 = 0; j4 < 4; ++j4)
                    wv[j4] = *(const float4*)&sW[k4 * 4 + dk][cg * 16 + j4 * 4];
                #pragma unroll
                for (int i = 0; i < 8; ++i) {
                    float hv = (dk == 0) ? h[i].x : (dk == 1) ? h[i].y : (dk == 2) ? h[i].z : h[i].w;
                    #pragma unroll
                    for (int j4 = 0; j4 < 4; ++j4) {
                        acc[i][j4 * 4 + 0] += hv * wv[j4].x;
                        acc[i][j4 * 4 + 1] += hv * wv[j4].y;
                        acc[i][j4 * 4 + 2] += hv * wv[j4].z;
                        acc[i][j4 * 4 + 3] += hv * wv[j4].w;
                    }
                }
            }
        }
    }
    bool isXR = (cg >= 8);
    int cbase = isXR ? (cg - 8) * 16 : cg * 16;
    float* OUT = isXR ? XR : XL;
    #pragma unroll
    for (int i = 0; i < 8; ++i) {
        int r = r0 + rg * 8 + i;
        if (r < nrows) {
            #pragma unroll
            for (int j4 = 0; j4 < 4; ++j4) {
                *(float4*)&OUT[(size_t)r * 128 + cbase + j4 * 4] =
                    make_float4(acc[i][j4 * 4], acc[i][j4 * 4 + 1], acc[i][j4 * 4 + 2], acc[i][j4 * 4 + 3]);
            }
        }
    }
}

// ---------------------------------------------------------------- fused GATv2 attention + aggregation
// one wave per node; 4 edges in flight (16 lanes / edge, 8 channels / lane);
// online softmax so each edge's xl row is read exactly once.
__global__ __launch_bounds__(256) void gat_agg_kernel(
    const float* __restrict__ xl, const float* __restrict__ xr,
    const int* __restrict__ rowptr, const int* __restrict__ col, const int* __restrict__ eid,
    const float* __restrict__ edge_attr, const float* __restrict__ loop_attr,
    const float* __restrict__ We, const float* __restrict__ att, const float* __restrict__ bias,
    float* __restrict__ out, int N, int E, int do_relu)
{
    int n = blockIdx.x * 4 + (threadIdx.x >> 6);
    if (n >= N) return;
    int lane = threadIdx.x & 63;
    int g = lane >> 4;       // edge-slot group 0..3
    int lg = lane & 15;
    int c0 = lg * 8;         // my 8 channels

    float attv[8], xrv[8], wev[4][8];
    #pragma unroll
    for (int j = 0; j < 8; ++j) {
        attv[j] = att[c0 + j];
        xrv[j]  = xr[(size_t)n * 128 + c0 + j];
    }
    #pragma unroll
    for (int k = 0; k < 4; ++k)
        #pragma unroll
        for (int j = 0; j < 8; ++j) wev[k][j] = We[k * 128 + c0 + j];

    int e0 = rowptr[n], e1 = rowptr[n + 1];
    float m = -INFINITY, den = 0.f;
    float acc[8];
    #pragma unroll
    for (int j = 0; j < 8; ++j) acc[j] = 0.f;

    for (int e = e0 + g; e < e1; e += 4) {
        int s  = col[e];
        int id = eid[e];
        const float* ea = (id < E) ? (edge_attr + (size_t)id * 4)
                                   : (loop_attr + (size_t)(id - E) * 4);
        float4 eav = *(const float4*)ea;
        const float* xls = xl + (size_t)s * 128 + c0;
        float4 x0 = *(const float4*)xls;
        float4 x1 = *(const float4*)(xls + 4);
        float xlv[8] = {x0.x, x0.y, x0.z, x0.w, x1.x, x1.y, x1.z, x1.w};
        float v = 0.f;
        #pragma unroll
        for (int j = 0; j < 8; ++j) {
            float u = xlv[j] + xrv[j]
                    + eav.x * wev[0][j] + eav.y * wev[1][j]
                    + eav.z * wev[2][j] + eav.w * wev[3][j];
            float lu = (u > 0.f) ? u : (SLOPE * u);
            v += lu * attv[j];
        }
        v += __shfl_xor(v, 1);
        v += __shfl_xor(v, 2);
        v += __shfl_xor(v, 4);
        v += __shfl_xor(v, 8);
        float mnew  = fmaxf(m, v);
        float scale = __expf(m - mnew);   // 0 on first edge (m=-inf)
        float wgt   = __expf(v - mnew);
        den = den * scale + wgt;
        #pragma unroll
        for (int j = 0; j < 8; ++j) acc[j] = acc[j] * scale + wgt * xlv[j];
        m = mnew;
    }
    // combine 4 groups (differing running maxima)
    float M = fmaxf(m, __shfl_xor(m, 16));
    M = fmaxf(M, __shfl_xor(M, 32));
    float sc = __expf(m - M);             // 0 for empty groups (m=-inf)
    float d2 = den * sc;
    d2 += __shfl_xor(d2, 16);
    d2 += __shfl_xor(d2, 32);
    float inv = 1.f / (d2 + 1e-16f);
    float o[8];
    #pragma unroll
    for (int j = 0; j < 8; ++j) {
        float a = acc[j] * sc;
        a += __shfl_xor(a, 16);
        a += __shfl_xor(a, 32);
        float val = a * inv + bias[c0 + j];
        o[j] = do_relu ? fmaxf(val, 0.f) : val;
    }
    if (g == 0) {
        *(float4*)&out[(size_t)n * 128 + c0]     = make_float4(o[0], o[1], o[2], o[3]);
        *(float4*)&out[(size_t)n * 128 + c0 + 4] = make_float4(o[4], o[5], o[6], o[7]);
    }
}

// ---------------------------------------------------------------- launch

static inline char* carve(char*& p, size_t bytes) {
    char* r = p;
    p += (bytes + 255) & ~(size_t)255;
    return r;
}

extern "C" void kernel_launch(void* const* d_in, const int* in_sizes, int n_in,
                              void* d_out, int out_size, void* d_ws, size_t ws_size,
                              hipStream_t stream)
{
    const int* edge_index = (const int*)d_in[0];
    int E = in_sizes[0] / 2;
    int N = in_sizes[2] / 128;
    const int* srcv = edge_index;
    const int* dstv = edge_index + E;
    const float* eattr = (const float*)d_in[1];
    const float* x = (const float*)d_in[2];

    char* p = (char*)d_ws;
    int*   deg    = (int*)  carve(p, (size_t)N * 4);
    int*   fill   = (int*)  carve(p, (size_t)N * 4);
    int*   rowptr = (int*)  carve(p, (size_t)(N + 1) * 4);
    int*   col    = (int*)  carve(p, (size_t)(E + N) * 4);
    int*   eid    = (int*)  carve(p, (size_t)(E + N) * 4);
    float* loopat = (float*)carve(p, (size_t)N * 16);
    float* xlb    = (float*)carve(p, (size_t)N * 512);
    float* xrb    = (float*)carve(p, (size_t)N * 512);

    hipMemsetAsync(deg,    0, (size_t)N * 4,  stream);
    hipMemsetAsync(fill,   0, (size_t)N * 4,  stream);
    hipMemsetAsync(loopat, 0, (size_t)N * 16, stream);

    count_deg_kernel<<<(E + 255) / 256, 256, 0, stream>>>(dstv, eattr, deg, loopat, E);
    scan_kernel<<<1, 1024, 0, stream>>>(deg, rowptr, N);
    fill_csr_kernel<<<(E + 255) / 256, 256, 0, stream>>>(srcv, dstv, rowptr, fill, col, eid, E);
    selfloop_kernel<<<(N + 255) / 256, 256, 0, stream>>>(rowptr, deg, col, eid, loopat, N, E);

    float* out = (float*)d_out;
    for (int li = 0; li < 3; ++li) {
        const float* Wl  = (const float*)d_in[3 + 5 * li + 0];
        const float* Wr  = (const float*)d_in[3 + 5 * li + 1];
        const float* Wep = (const float*)d_in[3 + 5 * li + 2];
        const float* atp = (const float*)d_in[3 + 5 * li + 3];
        const float* bp  = (const float*)d_in[3 + 5 * li + 4];
        const float* hin = (li == 0) ? x : out;
        gemm_xlxr_kernel<<<(N + 127) / 128, 256, 0, stream>>>(hin, Wl, Wr, xlb, xrb, N);
        gat_agg_kernel<<<(N + 3) / 4, 256, 0, stream>>>(xlb, xrb, rowptr, col, eid,
                                                        eattr, loopat, Wep, atp, bp,
                                                        out, N, E, li < 2 ? 1 : 0);
    }
}

// Round 2
// 1625.102 us; speedup vs baseline: 1.1995x; 1.1995x over previous
//
#include <hip/hip_runtime.h>
#include <hip/hip_bf16.h>
#include <cmath>

#define SLOPE 0.2f

// ---------------------------------------------------------------- preprocessing

__global__ __launch_bounds__(256) void count_deg_kernel(
    const int* __restrict__ dstv, int* __restrict__ deg, int E)
{
    int e = blockIdx.x * 256 + threadIdx.x;
    if (e >= E) return;
    atomicAdd(&deg[dstv[e]], 1);
}

// exclusive prefix over (deg[i]+1): rowptr[0]=0, rowptr[i+1]=sum_{j<=i}(deg[j]+1)
__global__ void scan_kernel(const int* __restrict__ deg, int* __restrict__ rowptr, int N)
{
    __shared__ int swsum[16];
    __shared__ int sbase[16];
    __shared__ int stotal;
    __shared__ int scarry;
    int t = threadIdx.x, lane = t & 63, w = t >> 6;
    if (t == 0) { scarry = 0; rowptr[0] = 0; }
    __syncthreads();
    for (int base = 0; base < N; base += 1024) {
        int i = base + t;
        int v = (i < N) ? (deg[i] + 1) : 0;
        #pragma unroll
        for (int off = 1; off < 64; off <<= 1) {
            int u = __shfl_up(v, off);
            if (lane >= off) v += u;
        }
        if (lane == 63) swsum[w] = v;
        __syncthreads();
        if (w == 0 && lane < 16) {
            int xv = swsum[lane];
            int orig = xv;
            #pragma unroll
            for (int off = 1; off < 16; off <<= 1) {
                int u = __shfl_up(xv, off);
                if (lane >= off) xv += u;
            }
            sbase[lane] = xv - orig;
            if (lane == 15) stotal = xv;
        }
        __syncthreads();
        if (i < N) rowptr[i + 1] = scarry + sbase[w] + v;
        __syncthreads();
        if (t == 0) scarry += stotal;
        __syncthreads();
    }
}

// scatter edges into CSR slots; also permute edge_attr into CSR order so the
// per-layer attention loop reads col[] and eattr_perm[] fully linearly.
__global__ __launch_bounds__(256) void fill_csr_kernel(
    const int* __restrict__ srcv, const int* __restrict__ dstv,
    const float* __restrict__ eattr,
    const int* __restrict__ rowptr, int* __restrict__ fill,
    int* __restrict__ col, float* __restrict__ eattr_perm, int E)
{
    int e = blockIdx.x * 256 + threadIdx.x;
    if (e >= E) return;
    int d = dstv[e];
    int pos = rowptr[d] + atomicAdd(&fill[d], 1);
    col[pos] = srcv[e];
    *(float4*)&eattr_perm[(size_t)pos * 4] = *(const float4*)&eattr[(size_t)e * 4];
}

// per node: write self-loop col entry; self-loop attr = mean of incoming
// edge_attr, summed serially from this node's own CSR row (no atomics).
__global__ __launch_bounds__(256) void selfloop_kernel(
    const int* __restrict__ rowptr, const int* __restrict__ deg,
    int* __restrict__ col, float* __restrict__ eattr_perm, int N)
{
    int n = blockIdx.x * 256 + threadIdx.x;
    if (n >= N) return;
    int e0 = rowptr[n], e1 = rowptr[n + 1];
    float4 s = make_float4(0.f, 0.f, 0.f, 0.f);
    for (int e = e0; e < e1 - 1; ++e) {
        float4 a = *(const float4*)&eattr_perm[(size_t)e * 4];
        s.x += a.x; s.y += a.y; s.z += a.z; s.w += a.w;
    }
    float inv = 1.0f / fmaxf((float)deg[n], 1.0f);
    s.x *= inv; s.y *= inv; s.z *= inv; s.w *= inv;
    int pos = e1 - 1;
    col[pos] = n;
    *(float4*)&eattr_perm[(size_t)pos * 4] = s;
}

// ---------------------------------------------------------------- fused xl/xr GEMM
// XL = H @ Wl, XR = H @ Wr.  H:[nrows,128], W:[128,128].
// block: 256 threads, 128-row tile, 256 virtual cols (=XL|XR), k-chunk 32.
__global__ __launch_bounds__(256, 2) void gemm_xlxr_kernel(
    const float* __restrict__ H, const float* __restrict__ Wl, const float* __restrict__ Wr,
    float* __restrict__ XL, float* __restrict__ XR, int nrows)
{
    __shared__ float sH[128][32];
    __shared__ float sW[32][256];
    int t = threadIdx.x;
    int r0 = blockIdx.x * 128;
    int rg = t >> 4;      // 16 row groups * 8 rows
    int cg = t & 15;      // 16 col groups * 16 cols
    float acc[8][16];
    #pragma unroll
    for (int i = 0; i < 8; ++i)
        #pragma unroll
        for (int j = 0; j < 16; ++j) acc[i][j] = 0.f;

    for (int kc = 0; kc < 128; kc += 32) {
        __syncthreads();
        #pragma unroll
        for (int li = 0; li < 4; ++li) {
            int idx = t + li * 256;           // 1024 = 128 rows * 8 float4
            int r = idx >> 3, k4 = idx & 7;
            int gr = r0 + r;
            float4 hv = make_float4(0.f, 0.f, 0.f, 0.f);
            if (gr < nrows) hv = *(const float4*)&H[(size_t)gr * 128 + kc + k4 * 4];
            *(float4*)&sH[r][k4 * 4] = hv;
        }
        #pragma unroll
        for (int li = 0; li < 4; ++li) {
            int idx = t + li * 256;           // 1024 = 32 rows * 32 float4 (per half)
            int k = idx >> 5, c4 = idx & 31;
            *(float4*)&sW[k][c4 * 4]       = *(const float4*)&Wl[(size_t)(kc + k) * 128 + c4 * 4];
            *(float4*)&sW[k][128 + c4 * 4] = *(const float4*)&Wr[(size_t)(kc + k) * 128 + c4 * 4];
        }
        __syncthreads();
        #pragma unroll
        for (int k4 = 0; k4 < 8; ++k4) {
            float4 h[8];
            #pragma unroll
            for (int i = 0; i < 8; ++i) h[i] = *(const float4*)&sH[rg * 8 + i][k4 * 4];
            #pragma unroll
            for (int dk = 0; dk < 4; ++dk) {
                float4 wv[4];
                #pragma unroll
                for (int j4 = 0; j4 < 4; ++j4)
                    wv[j4] = *(const float4*)&sW[k4 * 4 + dk][cg * 16 + j4 * 4];
                #pragma unroll
                for (int i = 0; i < 8; ++i) {
                    float hv = (dk == 0) ? h[i].x : (dk == 1) ? h[i].y : (dk == 2) ? h[i].z : h[i].w;
                    #pragma unroll
                    for (int j4 = 0; j4 < 4; ++j4) {
                        acc[i][j4 * 4 + 0] += hv * wv[j4].x;
                        acc[i][j4 * 4 + 1] += hv * wv[j4].y;
                        acc[i][j4 * 4 + 2] += hv * wv[j4].z;
                        acc[i][j4 * 4 + 3] += hv * wv[j4].w;
                    }
                }
            }
        }
    }
    bool isXR = (cg >= 8);
    int cbase = isXR ? (cg - 8) * 16 : cg * 16;
    float* OUT = isXR ? XR : XL;
    #pragma unroll
    for (int i = 0; i < 8; ++i) {
        int r = r0 + rg * 8 + i;
        if (r < nrows) {
            #pragma unroll
            for (int j4 = 0; j4 < 4; ++j4) {
                *(float4*)&OUT[(size_t)r * 128 + cbase + j4 * 4] =
                    make_float4(acc[i][j4 * 4], acc[i][j4 * 4 + 1], acc[i][j4 * 4 + 2], acc[i][j4 * 4 + 3]);
            }
        }
    }
}

// ---------------------------------------------------------------- fused GATv2 attention + aggregation
// one wave per node; 4 edges in flight (16 lanes / edge, 8 channels / lane);
// online softmax so each edge's xl row is read exactly once.
__global__ __launch_bounds__(256) void gat_agg_kernel(
    const float* __restrict__ xl, const float* __restrict__ xr,
    const int* __restrict__ rowptr, const int* __restrict__ col,
    const float* __restrict__ eattr_perm,
    const float* __restrict__ We, const float* __restrict__ att, const float* __restrict__ bias,
    float* __restrict__ out, int N, int do_relu)
{
    int n = blockIdx.x * 4 + (threadIdx.x >> 6);
    if (n >= N) return;
    int lane = threadIdx.x & 63;
    int g = lane >> 4;       // edge-slot group 0..3
    int lg = lane & 15;
    int c0 = lg * 8;         // my 8 channels

    float attv[8], xrv[8], wev[4][8];
    #pragma unroll
    for (int j = 0; j < 8; ++j) {
        attv[j] = att[c0 + j];
        xrv[j]  = xr[(size_t)n * 128 + c0 + j];
    }
    #pragma unroll
    for (int k = 0; k < 4; ++k)
        #pragma unroll
        for (int j = 0; j < 8; ++j) wev[k][j] = We[k * 128 + c0 + j];

    int e0 = rowptr[n], e1 = rowptr[n + 1];
    float m = -INFINITY, den = 0.f;
    float acc[8];
    #pragma unroll
    for (int j = 0; j < 8; ++j) acc[j] = 0.f;

    for (int e = e0 + g; e < e1; e += 4) {
        int s = col[e];
        float4 eav = *(const float4*)&eattr_perm[(size_t)e * 4];
        const float* xls = xl + (size_t)s * 128 + c0;
        float4 x0 = *(const float4*)xls;
        float4 x1 = *(const float4*)(xls + 4);
        float xlv[8] = {x0.x, x0.y, x0.z, x0.w, x1.x, x1.y, x1.z, x1.w};
        float v = 0.f;
        #pragma unroll
        for (int j = 0; j < 8; ++j) {
            float u = xlv[j] + xrv[j]
                    + eav.x * wev[0][j] + eav.y * wev[1][j]
                    + eav.z * wev[2][j] + eav.w * wev[3][j];
            float lu = (u > 0.f) ? u : (SLOPE * u);
            v += lu * attv[j];
        }
        v += __shfl_xor(v, 1);
        v += __shfl_xor(v, 2);
        v += __shfl_xor(v, 4);
        v += __shfl_xor(v, 8);
        float mnew  = fmaxf(m, v);
        float scale = __expf(m - mnew);   // 0 on first edge (m=-inf)
        float wgt   = __expf(v - mnew);
        den = den * scale + wgt;
        #pragma unroll
        for (int j = 0; j < 8; ++j) acc[j] = acc[j] * scale + wgt * xlv[j];
        m = mnew;
    }
    // combine 4 groups (differing running maxima)
    float M = fmaxf(m, __shfl_xor(m, 16));
    M = fmaxf(M, __shfl_xor(M, 32));
    float sc = __expf(m - M);             // 0 for empty groups (m=-inf)
    float d2 = den * sc;
    d2 += __shfl_xor(d2, 16);
    d2 += __shfl_xor(d2, 32);
    float inv = 1.f / (d2 + 1e-16f);
    float o[8];
    #pragma unroll
    for (int j = 0; j < 8; ++j) {
        float a = acc[j] * sc;
        a += __shfl_xor(a, 16);
        a += __shfl_xor(a, 32);
        float val = a * inv + bias[c0 + j];
        o[j] = do_relu ? fmaxf(val, 0.f) : val;
    }
    if (g == 0) {
        *(float4*)&out[(size_t)n * 128 + c0]     = make_float4(o[0], o[1], o[2], o[3]);
        *(float4*)&out[(size_t)n * 128 + c0 + 4] = make_float4(o[4], o[5], o[6], o[7]);
    }
}

// ---------------------------------------------------------------- launch

static inline char* carve(char*& p, size_t bytes) {
    char* r = p;
    p += (bytes + 255) & ~(size_t)255;
    return r;
}

extern "C" void kernel_launch(void* const* d_in, const int* in_sizes, int n_in,
                              void* d_out, int out_size, void* d_ws, size_t ws_size,
                              hipStream_t stream)
{
    const int* edge_index = (const int*)d_in[0];
    int E = in_sizes[0] / 2;
    int N = in_sizes[2] / 128;
    const int* srcv = edge_index;
    const int* dstv = edge_index + E;
    const float* eattr = (const float*)d_in[1];
    const float* x = (const float*)d_in[2];

    char* p = (char*)d_ws;
    int*   deg    = (int*)  carve(p, (size_t)N * 4);
    int*   fill   = (int*)  carve(p, (size_t)N * 4);
    int*   rowptr = (int*)  carve(p, (size_t)(N + 1) * 4);
    int*   col    = (int*)  carve(p, (size_t)(E + N) * 4);
    float* eperm  = (float*)carve(p, (size_t)(E + N) * 16);
    float* xlb    = (float*)carve(p, (size_t)N * 512);
    float* xrb    = (float*)carve(p, (size_t)N * 512);

    hipMemsetAsync(deg,  0, (size_t)N * 4, stream);
    hipMemsetAsync(fill, 0, (size_t)N * 4, stream);

    count_deg_kernel<<<(E + 255) / 256, 256, 0, stream>>>(dstv, deg, E);
    scan_kernel<<<1, 1024, 0, stream>>>(deg, rowptr, N);
    fill_csr_kernel<<<(E + 255) / 256, 256, 0, stream>>>(srcv, dstv, eattr, rowptr, fill, col, eperm, E);
    selfloop_kernel<<<(N + 255) / 256, 256, 0, stream>>>(rowptr, deg, col, eperm, N);

    float* out = (float*)d_out;
    for (int li = 0; li < 3; ++li) {
        const float* Wl  = (const float*)d_in[3 + 5 * li + 0];
        const float* Wr  = (const float*)d_in[3 + 5 * li + 1];
        const float* Wep = (const float*)d_in[3 + 5 * li + 2];
        const float* atp = (const float*)d_in[3 + 5 * li + 3];
        const float* bp  = (const float*)d_in[3 + 5 * li + 4];
        const float* hin = (li == 0) ? x : out;
        gemm_xlxr_kernel<<<(N + 127) / 128, 256, 0, stream>>>(hin, Wl, Wr, xlb, xrb, N);
        gat_agg_kernel<<<(N + 3) / 4, 256, 0, stream>>>(xlb, xrb, rowptr, col, eperm,
                                                        Wep, atp, bp, out, N, li < 2 ? 1 : 0);
    }
}

// Round 3
// 985.750 us; speedup vs baseline: 1.9774x; 1.6486x over previous
//
#include <hip/hip_runtime.h>
#include <hip/hip_bf16.h>
#include <cmath>

#define SLOPE 0.2f

typedef __attribute__((ext_vector_type(8))) short bf16x8;
typedef __attribute__((ext_vector_type(4))) float f32x4;

__device__ __forceinline__ unsigned short bf16_rne(float x) {
    unsigned int b = __float_as_uint(x);
    b += 0x7FFFu + ((b >> 16) & 1u);
    return (unsigned short)(b >> 16);
}
__device__ __forceinline__ float bf16_tof(unsigned short h) {
    return __uint_as_float(((unsigned int)h) << 16);
}

// ---------------------------------------------------------------- preprocessing

__global__ __launch_bounds__(256) void count_deg_kernel(
    const int* __restrict__ dstv, int* __restrict__ deg, int E)
{
    int e = blockIdx.x * 256 + threadIdx.x;
    if (e >= E) return;
    atomicAdd(&deg[dstv[e]], 1);
}

// exclusive prefix over (deg[i]+1): rowptr[0]=0, rowptr[i+1]=sum_{j<=i}(deg[j]+1)
__global__ void scan_kernel(const int* __restrict__ deg, int* __restrict__ rowptr, int N)
{
    __shared__ int swsum[16];
    __shared__ int sbase[16];
    __shared__ int stotal;
    __shared__ int scarry;
    int t = threadIdx.x, lane = t & 63, w = t >> 6;
    if (t == 0) { scarry = 0; rowptr[0] = 0; }
    __syncthreads();
    for (int base = 0; base < N; base += 1024) {
        int i = base + t;
        int v = (i < N) ? (deg[i] + 1) : 0;
        #pragma unroll
        for (int off = 1; off < 64; off <<= 1) {
            int u = __shfl_up(v, off);
            if (lane >= off) v += u;
        }
        if (lane == 63) swsum[w] = v;
        __syncthreads();
        if (w == 0 && lane < 16) {
            int xv = swsum[lane];
            int orig = xv;
            #pragma unroll
            for (int off = 1; off < 16; off <<= 1) {
                int u = __shfl_up(xv, off);
                if (lane >= off) xv += u;
            }
            sbase[lane] = xv - orig;
            if (lane == 15) stotal = xv;
        }
        __syncthreads();
        if (i < N) rowptr[i + 1] = scarry + sbase[w] + v;
        __syncthreads();
        if (t == 0) scarry += stotal;
        __syncthreads();
    }
}

__global__ __launch_bounds__(256) void fill_csr_kernel(
    const int* __restrict__ srcv, const int* __restrict__ dstv,
    const float* __restrict__ eattr,
    const int* __restrict__ rowptr, int* __restrict__ fill,
    int* __restrict__ col, float* __restrict__ eattr_perm, int E)
{
    int e = blockIdx.x * 256 + threadIdx.x;
    if (e >= E) return;
    int d = dstv[e];
    int pos = rowptr[d] + atomicAdd(&fill[d], 1);
    col[pos] = srcv[e];
    *(float4*)&eattr_perm[(size_t)pos * 4] = *(const float4*)&eattr[(size_t)e * 4];
}

__global__ __launch_bounds__(256) void selfloop_kernel(
    const int* __restrict__ rowptr, const int* __restrict__ deg,
    int* __restrict__ col, float* __restrict__ eattr_perm, int N)
{
    int n = blockIdx.x * 256 + threadIdx.x;
    if (n >= N) return;
    int e0 = rowptr[n], e1 = rowptr[n + 1];
    float4 s = make_float4(0.f, 0.f, 0.f, 0.f);
    for (int e = e0; e < e1 - 1; ++e) {
        float4 a = *(const float4*)&eattr_perm[(size_t)e * 4];
        s.x += a.x; s.y += a.y; s.z += a.z; s.w += a.w;
    }
    float inv = 1.0f / fmaxf((float)deg[n], 1.0f);
    s.x *= inv; s.y *= inv; s.z *= inv; s.w *= inv;
    int pos = e1 - 1;
    col[pos] = n;
    *(float4*)&eattr_perm[(size_t)pos * 4] = s;
}

// W prep: Thi/Tlo[c][k] = bf16 hi/lo split of W[k][c], c in [0,256) = Wl|Wr.
__global__ __launch_bounds__(128) void wprep_kernel(
    const float* __restrict__ Wl, const float* __restrict__ Wr,
    unsigned short* __restrict__ Thi, unsigned short* __restrict__ Tlo)
{
    int c = blockIdx.x;      // 0..255
    int k = threadIdx.x;     // 0..127
    const float* W = (c < 128) ? Wl : Wr;
    float v = W[(size_t)k * 128 + (c & 127)];
    unsigned short h = bf16_rne(v);
    float lo = v - bf16_tof(h);
    Thi[(size_t)c * 128 + k] = h;
    Tlo[(size_t)c * 128 + k] = bf16_rne(lo);
}

// ---------------------------------------------------------------- MFMA GEMM (bf16x3)
// XL|XR = H @ [Wl|Wr].  H:[nrows,128] fp32, T*:[256][128] bf16 col-major.
// block = 256 thr = 4 waves; 64 rows x 256 cols per block; wave = 64-col quadrant.
// mfma_f32_16x16x32_bf16: A[l&15][8*(l>>4)+j], B[8*(l>>4)+j][l&15],
//                         C col=l&15, row=(l>>4)*4+reg   (m89/m91-verified)
__global__ __launch_bounds__(256, 2) void gemm_mfma_kernel(
    const float* __restrict__ H,
    const unsigned short* __restrict__ Thi, const unsigned short* __restrict__ Tlo,
    float* __restrict__ XL, float* __restrict__ XR, int nrows)
{
    __shared__ unsigned short sHi[64 * 128];
    __shared__ unsigned short sLo[64 * 128];
    int t = threadIdx.x;
    int r0 = blockIdx.x * 64;

    // stage 64 rows of H as bf16 hi/lo, XOR-swizzled 16B slots
    #pragma unroll
    for (int i = 0; i < 4; ++i) {
        int row = i * 16 + (t >> 4);
        int chunk = t & 15;                 // 8-float chunk within row
        int gr = min(r0 + row, nrows - 1);
        float4 a = *(const float4*)&H[(size_t)gr * 128 + chunk * 8];
        float4 b = *(const float4*)&H[(size_t)gr * 128 + chunk * 8 + 4];
        float v[8] = {a.x, a.y, a.z, a.w, b.x, b.y, b.z, b.w};
        union { bf16x8 v; unsigned short u[8]; } hv, lv;
        #pragma unroll
        for (int j = 0; j < 8; ++j) {
            unsigned short h = bf16_rne(v[j]);
            hv.u[j] = h;
            lv.u[j] = bf16_rne(v[j] - bf16_tof(h));
        }
        int slot = chunk ^ (row & 7);
        *(bf16x8*)&sHi[row * 128 + slot * 8] = hv.v;
        *(bf16x8*)&sLo[row * 128 + slot * 8] = lv.v;
    }
    __syncthreads();

    int w  = t >> 6;        // wave -> 64-col quadrant
    int l  = t & 63;
    int lr = l & 15;        // A row / B col / C col
    int lk = l >> 4;        // k-subgroup
    int cbase = w * 64;

    f32x4 acc[4][4];
    #pragma unroll
    for (int i = 0; i < 4; ++i)
        #pragma unroll
        for (int j = 0; j < 4; ++j)
            acc[i][j] = (f32x4){0.f, 0.f, 0.f, 0.f};

    #pragma unroll
    for (int k0 = 0; k0 < 128; k0 += 32) {
        bf16x8 ah[4], al[4];
        #pragma unroll
        for (int rt = 0; rt < 4; ++rt) {
            int row = rt * 16 + lr;
            int chunk = (k0 >> 3) + lk;
            int slot = chunk ^ (row & 7);
            ah[rt] = *(const bf16x8*)&sHi[row * 128 + slot * 8];
            al[rt] = *(const bf16x8*)&sLo[row * 128 + slot * 8];
        }
        int k = k0 + lk * 8;
        #pragma unroll
        for (int ct = 0; ct < 4; ++ct) {
            int c = cbase + ct * 16 + lr;
            bf16x8 bh = *(const bf16x8*)&Thi[(size_t)c * 128 + k];
            bf16x8 bl = *(const bf16x8*)&Tlo[(size_t)c * 128 + k];
            #pragma unroll
            for (int rt = 0; rt < 4; ++rt) {
                acc[rt][ct] = __builtin_amdgcn_mfma_f32_16x16x32_bf16(ah[rt], bh, acc[rt][ct], 0, 0, 0);
                acc[rt][ct] = __builtin_amdgcn_mfma_f32_16x16x32_bf16(al[rt], bh, acc[rt][ct], 0, 0, 0);
                acc[rt][ct] = __builtin_amdgcn_mfma_f32_16x16x32_bf16(ah[rt], bl, acc[rt][ct], 0, 0, 0);
            }
        }
    }

    // store: quadrant w<2 -> XL, else XR (wave-uniform)
    float* OUT = (w < 2) ? XL : XR;
    int ccol0 = (cbase & 127);
    #pragma unroll
    for (int rt = 0; rt < 4; ++rt) {
        #pragma unroll
        for (int ct = 0; ct < 4; ++ct) {
            int cc = ccol0 + ct * 16 + lr;
            #pragma unroll
            for (int q = 0; q < 4; ++q) {
                int r = r0 + rt * 16 + lk * 4 + q;
                if (r < nrows) OUT[(size_t)r * 128 + cc] = acc[rt][ct][q];
            }
        }
    }
}

// ---------------------------------------------------------------- fused GATv2 attention + aggregation
__global__ __launch_bounds__(256) void gat_agg_kernel(
    const float* __restrict__ xl, const float* __restrict__ xr,
    const int* __restrict__ rowptr, const int* __restrict__ col,
    const float* __restrict__ eattr_perm,
    const float* __restrict__ We, const float* __restrict__ att, const float* __restrict__ bias,
    float* __restrict__ out, int N, int do_relu)
{
    int n = blockIdx.x * 4 + (threadIdx.x >> 6);
    if (n >= N) return;
    int lane = threadIdx.x & 63;
    int g = lane >> 4;
    int lg = lane & 15;
    int c0 = lg * 8;

    float attv[8], xrv[8], wev[4][8];
    #pragma unroll
    for (int j = 0; j < 8; ++j) {
        attv[j] = att[c0 + j];
        xrv[j]  = xr[(size_t)n * 128 + c0 + j];
    }
    #pragma unroll
    for (int k = 0; k < 4; ++k)
        #pragma unroll
        for (int j = 0; j < 8; ++j) wev[k][j] = We[k * 128 + c0 + j];

    int e0 = rowptr[n], e1 = rowptr[n + 1];
    float m = -INFINITY, den = 0.f;
    float acc[8];
    #pragma unroll
    for (int j = 0; j < 8; ++j) acc[j] = 0.f;

    for (int e = e0 + g; e < e1; e += 4) {
        int s = col[e];
        float4 eav = *(const float4*)&eattr_perm[(size_t)e * 4];
        const float* xls = xl + (size_t)s * 128 + c0;
        float4 x0 = *(const float4*)xls;
        float4 x1 = *(const float4*)(xls + 4);
        float xlv[8] = {x0.x, x0.y, x0.z, x0.w, x1.x, x1.y, x1.z, x1.w};
        float v = 0.f;
        #pragma unroll
        for (int j = 0; j < 8; ++j) {
            float u = xlv[j] + xrv[j]
                    + eav.x * wev[0][j] + eav.y * wev[1][j]
                    + eav.z * wev[2][j] + eav.w * wev[3][j];
            float lu = (u > 0.f) ? u : (SLOPE * u);
            v += lu * attv[j];
        }
        v += __shfl_xor(v, 1);
        v += __shfl_xor(v, 2);
        v += __shfl_xor(v, 4);
        v += __shfl_xor(v, 8);
        float mnew  = fmaxf(m, v);
        float scale = __expf(m - mnew);
        float wgt   = __expf(v - mnew);
        den = den * scale + wgt;
        #pragma unroll
        for (int j = 0; j < 8; ++j) acc[j] = acc[j] * scale + wgt * xlv[j];
        m = mnew;
    }
    float M = fmaxf(m, __shfl_xor(m, 16));
    M = fmaxf(M, __shfl_xor(M, 32));
    float sc = __expf(m - M);
    float d2 = den * sc;
    d2 += __shfl_xor(d2, 16);
    d2 += __shfl_xor(d2, 32);
    float inv = 1.f / (d2 + 1e-16f);
    float o[8];
    #pragma unroll
    for (int j = 0; j < 8; ++j) {
        float a = acc[j] * sc;
        a += __shfl_xor(a, 16);
        a += __shfl_xor(a, 32);
        float val = a * inv + bias[c0 + j];
        o[j] = do_relu ? fmaxf(val, 0.f) : val;
    }
    if (g == 0) {
        *(float4*)&out[(size_t)n * 128 + c0]     = make_float4(o[0], o[1], o[2], o[3]);
        *(float4*)&out[(size_t)n * 128 + c0 + 4] = make_float4(o[4], o[5], o[6], o[7]);
    }
}

// ---------------------------------------------------------------- launch

static inline char* carve(char*& p, size_t bytes) {
    char* r = p;
    p += (bytes + 255) & ~(size_t)255;
    return r;
}

extern "C" void kernel_launch(void* const* d_in, const int* in_sizes, int n_in,
                              void* d_out, int out_size, void* d_ws, size_t ws_size,
                              hipStream_t stream)
{
    const int* edge_index = (const int*)d_in[0];
    int E = in_sizes[0] / 2;
    int N = in_sizes[2] / 128;
    const int* srcv = edge_index;
    const int* dstv = edge_index + E;
    const float* eattr = (const float*)d_in[1];
    const float* x = (const float*)d_in[2];

    char* p = (char*)d_ws;
    int*   deg    = (int*)  carve(p, (size_t)N * 4);
    int*   fill   = (int*)  carve(p, (size_t)N * 4);
    int*   rowptr = (int*)  carve(p, (size_t)(N + 1) * 4);
    int*   col    = (int*)  carve(p, (size_t)(E + N) * 4);
    float* eperm  = (float*)carve(p, (size_t)(E + N) * 16);
    float* xlb    = (float*)carve(p, (size_t)N * 512);
    float* xrb    = (float*)carve(p, (size_t)N * 512);
    unsigned short* Thi = (unsigned short*)carve(p, (size_t)3 * 256 * 128 * 2);
    unsigned short* Tlo = (unsigned short*)carve(p, (size_t)3 * 256 * 128 * 2);

    hipMemsetAsync(deg,  0, (size_t)N * 4, stream);
    hipMemsetAsync(fill, 0, (size_t)N * 4, stream);

    count_deg_kernel<<<(E + 255) / 256, 256, 0, stream>>>(dstv, deg, E);
    scan_kernel<<<1, 1024, 0, stream>>>(deg, rowptr, N);
    fill_csr_kernel<<<(E + 255) / 256, 256, 0, stream>>>(srcv, dstv, eattr, rowptr, fill, col, eperm, E);
    selfloop_kernel<<<(N + 255) / 256, 256, 0, stream>>>(rowptr, deg, col, eperm, N);

    for (int li = 0; li < 3; ++li) {
        const float* Wl = (const float*)d_in[3 + 5 * li + 0];
        const float* Wr = (const float*)d_in[3 + 5 * li + 1];
        wprep_kernel<<<256, 128, 0, stream>>>(Wl, Wr,
                                              Thi + (size_t)li * 256 * 128,
                                              Tlo + (size_t)li * 256 * 128);
    }

    float* out = (float*)d_out;
    for (int li = 0; li < 3; ++li) {
        const float* Wep = (const float*)d_in[3 + 5 * li + 2];
        const float* atp = (const float*)d_in[3 + 5 * li + 3];
        const float* bp  = (const float*)d_in[3 + 5 * li + 4];
        const float* hin = (li == 0) ? x : out;
        gemm_mfma_kernel<<<(N + 63) / 64, 256, 0, stream>>>(
            hin, Thi + (size_t)li * 256 * 128, Tlo + (size_t)li * 256 * 128, xlb, xrb, N);
        gat_agg_kernel<<<(N + 3) / 4, 256, 0, stream>>>(xlb, xrb, rowptr, col, eperm,
                                                        Wep, atp, bp, out, N, li < 2 ? 1 : 0);
    }
}

// Round 4
// 890.943 us; speedup vs baseline: 2.1879x; 1.1064x over previous
//
#include <hip/hip_runtime.h>
#include <hip/hip_bf16.h>
#include <cmath>

#define SLOPE 0.2f

typedef __attribute__((ext_vector_type(8))) short bf16x8;
typedef __attribute__((ext_vector_type(4))) float f32x4;

__device__ __forceinline__ unsigned short bf16_rne(float x) {
    unsigned int b = __float_as_uint(x);
    b += 0x7FFFu + ((b >> 16) & 1u);
    return (unsigned short)(b >> 16);
}
__device__ __forceinline__ float bf16_tof(unsigned short h) {
    return __uint_as_float(((unsigned int)h) << 16);
}

// ---------------------------------------------------------------- preprocessing

__global__ __launch_bounds__(256) void count_deg_kernel(
    const int* __restrict__ dstv, int* __restrict__ deg, int E)
{
    int e = blockIdx.x * 256 + threadIdx.x;
    if (e >= E) return;
    atomicAdd(&deg[dstv[e]], 1);
}

// exclusive prefix over (deg[i]+1): rowptr[0]=0, rowptr[i+1]=sum_{j<=i}(deg[j]+1)
__global__ void scan_kernel(const int* __restrict__ deg, int* __restrict__ rowptr, int N)
{
    __shared__ int swsum[16];
    __shared__ int sbase[16];
    __shared__ int stotal;
    __shared__ int scarry;
    int t = threadIdx.x, lane = t & 63, w = t >> 6;
    if (t == 0) { scarry = 0; rowptr[0] = 0; }
    __syncthreads();
    for (int base = 0; base < N; base += 1024) {
        int i = base + t;
        int v = (i < N) ? (deg[i] + 1) : 0;
        #pragma unroll
        for (int off = 1; off < 64; off <<= 1) {
            int u = __shfl_up(v, off);
            if (lane >= off) v += u;
        }
        if (lane == 63) swsum[w] = v;
        __syncthreads();
        if (w == 0 && lane < 16) {
            int xv = swsum[lane];
            int orig = xv;
            #pragma unroll
            for (int off = 1; off < 16; off <<= 1) {
                int u = __shfl_up(xv, off);
                if (lane >= off) xv += u;
            }
            sbase[lane] = xv - orig;
            if (lane == 15) stotal = xv;
        }
        __syncthreads();
        if (i < N) rowptr[i + 1] = scarry + sbase[w] + v;
        __syncthreads();
        if (t == 0) scarry += stotal;
        __syncthreads();
    }
}

__global__ __launch_bounds__(256) void fill_csr_kernel(
    const int* __restrict__ srcv, const int* __restrict__ dstv,
    const float* __restrict__ eattr,
    const int* __restrict__ rowptr, int* __restrict__ fill,
    int* __restrict__ col, float* __restrict__ eattr_perm, int E)
{
    int e = blockIdx.x * 256 + threadIdx.x;
    if (e >= E) return;
    int d = dstv[e];
    int pos = rowptr[d] + atomicAdd(&fill[d], 1);
    col[pos] = srcv[e];
    *(float4*)&eattr_perm[(size_t)pos * 4] = *(const float4*)&eattr[(size_t)e * 4];
}

__global__ __launch_bounds__(256) void selfloop_kernel(
    const int* __restrict__ rowptr, const int* __restrict__ deg,
    int* __restrict__ col, float* __restrict__ eattr_perm, int N)
{
    int n = blockIdx.x * 256 + threadIdx.x;
    if (n >= N) return;
    int e0 = rowptr[n], e1 = rowptr[n + 1];
    float4 s = make_float4(0.f, 0.f, 0.f, 0.f);
    for (int e = e0; e < e1 - 1; ++e) {
        float4 a = *(const float4*)&eattr_perm[(size_t)e * 4];
        s.x += a.x; s.y += a.y; s.z += a.z; s.w += a.w;
    }
    float inv = 1.0f / fmaxf((float)deg[n], 1.0f);
    s.x *= inv; s.y *= inv; s.z *= inv; s.w *= inv;
    int pos = e1 - 1;
    col[pos] = n;
    *(float4*)&eattr_perm[(size_t)pos * 4] = s;
}

// W prep: Thi/Tlo[c][k] = bf16 hi/lo split of W[k][c], c in [0,256) = Wl|Wr.
__global__ __launch_bounds__(128) void wprep_kernel(
    const float* __restrict__ Wl, const float* __restrict__ Wr,
    unsigned short* __restrict__ Thi, unsigned short* __restrict__ Tlo)
{
    int c = blockIdx.x;      // 0..255
    int k = threadIdx.x;     // 0..127
    const float* W = (c < 128) ? Wl : Wr;
    float v = W[(size_t)k * 128 + (c & 127)];
    unsigned short h = bf16_rne(v);
    float lo = v - bf16_tof(h);
    Thi[(size_t)c * 128 + k] = h;
    Tlo[(size_t)c * 128 + k] = bf16_rne(lo);
}

// ---------------------------------------------------------------- MFMA GEMM (bf16x3)
// XLH (bf16) | XR (fp32) = H @ [Wl|Wr].  H:[nrows,128] fp32, T*:[256][128] bf16 col-major.
// block = 256 thr = 4 waves; 64 rows x 256 cols per block; wave = 64-col quadrant.
// mfma_f32_16x16x32_bf16: A[l&15][8*(l>>4)+j], B[8*(l>>4)+j][l&15],
//                         C col=l&15, row=(l>>4)*4+reg   (m89/m91-verified)
__global__ __launch_bounds__(256, 2) void gemm_mfma_kernel(
    const float* __restrict__ H,
    const unsigned short* __restrict__ Thi, const unsigned short* __restrict__ Tlo,
    unsigned short* __restrict__ XLH, float* __restrict__ XR, int nrows)
{
    __shared__ unsigned short sHi[64 * 128];
    __shared__ unsigned short sLo[64 * 128];
    int t = threadIdx.x;
    int r0 = blockIdx.x * 64;

    // stage 64 rows of H as bf16 hi/lo, XOR-swizzled 16B slots
    #pragma unroll
    for (int i = 0; i < 4; ++i) {
        int row = i * 16 + (t >> 4);
        int chunk = t & 15;                 // 8-float chunk within row
        int gr = min(r0 + row, nrows - 1);
        float4 a = *(const float4*)&H[(size_t)gr * 128 + chunk * 8];
        float4 b = *(const float4*)&H[(size_t)gr * 128 + chunk * 8 + 4];
        float v[8] = {a.x, a.y, a.z, a.w, b.x, b.y, b.z, b.w};
        union { bf16x8 v; unsigned short u[8]; } hv, lv;
        #pragma unroll
        for (int j = 0; j < 8; ++j) {
            unsigned short h = bf16_rne(v[j]);
            hv.u[j] = h;
            lv.u[j] = bf16_rne(v[j] - bf16_tof(h));
        }
        int slot = chunk ^ (row & 7);
        *(bf16x8*)&sHi[row * 128 + slot * 8] = hv.v;
        *(bf16x8*)&sLo[row * 128 + slot * 8] = lv.v;
    }
    __syncthreads();

    int w  = t >> 6;        // wave -> 64-col quadrant
    int l  = t & 63;
    int lr = l & 15;        // A row / B col / C col
    int lk = l >> 4;        // k-subgroup
    int cbase = w * 64;

    f32x4 acc[4][4];
    #pragma unroll
    for (int i = 0; i < 4; ++i)
        #pragma unroll
        for (int j = 0; j < 4; ++j)
            acc[i][j] = (f32x4){0.f, 0.f, 0.f, 0.f};

    #pragma unroll
    for (int k0 = 0; k0 < 128; k0 += 32) {
        bf16x8 ah[4], al[4];
        #pragma unroll
        for (int rt = 0; rt < 4; ++rt) {
            int row = rt * 16 + lr;
            int chunk = (k0 >> 3) + lk;
            int slot = chunk ^ (row & 7);
            ah[rt] = *(const bf16x8*)&sHi[row * 128 + slot * 8];
            al[rt] = *(const bf16x8*)&sLo[row * 128 + slot * 8];
        }
        int k = k0 + lk * 8;
        #pragma unroll
        for (int ct = 0; ct < 4; ++ct) {
            int c = cbase + ct * 16 + lr;
            bf16x8 bh = *(const bf16x8*)&Thi[(size_t)c * 128 + k];
            bf16x8 bl = *(const bf16x8*)&Tlo[(size_t)c * 128 + k];
            #pragma unroll
            for (int rt = 0; rt < 4; ++rt) {
                acc[rt][ct] = __builtin_amdgcn_mfma_f32_16x16x32_bf16(ah[rt], bh, acc[rt][ct], 0, 0, 0);
                acc[rt][ct] = __builtin_amdgcn_mfma_f32_16x16x32_bf16(al[rt], bh, acc[rt][ct], 0, 0, 0);
                acc[rt][ct] = __builtin_amdgcn_mfma_f32_16x16x32_bf16(ah[rt], bl, acc[rt][ct], 0, 0, 0);
            }
        }
    }

    int ccol0 = (cbase & 127);
    if (w < 2) {
        // XL in bf16
        #pragma unroll
        for (int rt = 0; rt < 4; ++rt)
            #pragma unroll
            for (int ct = 0; ct < 4; ++ct) {
                int cc = ccol0 + ct * 16 + lr;
                #pragma unroll
                for (int q = 0; q < 4; ++q) {
                    int r = r0 + rt * 16 + lk * 4 + q;
                    if (r < nrows) XLH[(size_t)r * 128 + cc] = bf16_rne(acc[rt][ct][q]);
                }
            }
    } else {
        #pragma unroll
        for (int rt = 0; rt < 4; ++rt)
            #pragma unroll
            for (int ct = 0; ct < 4; ++ct) {
                int cc = ccol0 + ct * 16 + lr;
                #pragma unroll
                for (int q = 0; q < 4; ++q) {
                    int r = r0 + rt * 16 + lk * 4 + q;
                    if (r < nrows) XR[(size_t)r * 128 + cc] = acc[rt][ct][q];
                }
            }
    }
}

// ---------------------------------------------------------------- fused GATv2 attention + aggregation
// each wave processes 4 consecutive nodes (att/We hoisted); per node:
// 4 edges in flight (16 lanes/edge, 8 ch/lane), online softmax, bf16 xl gather.
__global__ __launch_bounds__(256) void gat_agg_kernel(
    const unsigned short* __restrict__ xlh, const float* __restrict__ xr,
    const int* __restrict__ rowptr, const int* __restrict__ col,
    const float* __restrict__ eattr_perm,
    const float* __restrict__ We, const float* __restrict__ att, const float* __restrict__ bias,
    float* __restrict__ out, int N, int do_relu)
{
    int w = threadIdx.x >> 6;
    int lane = threadIdx.x & 63;
    int g = lane >> 4;
    int lg = lane & 15;
    int c0 = lg * 8;

    float attv[8], wev[4][8], bv[8];
    #pragma unroll
    for (int j = 0; j < 8; ++j) { attv[j] = att[c0 + j]; bv[j] = bias[c0 + j]; }
    #pragma unroll
    for (int k = 0; k < 4; ++k)
        #pragma unroll
        for (int j = 0; j < 8; ++j) wev[k][j] = We[k * 128 + c0 + j];

    int nbase = (blockIdx.x * 4 + w) * 4;
    for (int i = 0; i < 4; ++i) {
        int n = nbase + i;
        if (n >= N) return;           // wave-uniform

        float xrv[8];
        {
            float4 a = *(const float4*)&xr[((size_t)n << 7) + c0];
            float4 b = *(const float4*)&xr[((size_t)n << 7) + c0 + 4];
            xrv[0] = a.x; xrv[1] = a.y; xrv[2] = a.z; xrv[3] = a.w;
            xrv[4] = b.x; xrv[5] = b.y; xrv[6] = b.z; xrv[7] = b.w;
        }

        int e0 = rowptr[n], e1 = rowptr[n + 1];
        float m = -INFINITY, den = 0.f;
        float acc[8];
        #pragma unroll
        for (int j = 0; j < 8; ++j) acc[j] = 0.f;

        for (int e = e0 + g; e < e1; e += 4) {
            int s = col[e];
            float4 eav = *(const float4*)&eattr_perm[(size_t)e * 4];
            union { bf16x8 v; unsigned short u[8]; } xv;
            xv.v = *(const bf16x8*)&xlh[((size_t)(unsigned)s << 7) + c0];
            float xlv[8];
            #pragma unroll
            for (int j = 0; j < 8; ++j) xlv[j] = bf16_tof(xv.u[j]);
            float v = 0.f;
            #pragma unroll
            for (int j = 0; j < 8; ++j) {
                float u = xlv[j] + xrv[j]
                        + eav.x * wev[0][j] + eav.y * wev[1][j]
                        + eav.z * wev[2][j] + eav.w * wev[3][j];
                float lu = (u > 0.f) ? u : (SLOPE * u);
                v += lu * attv[j];
            }
            v += __shfl_xor(v, 1);
            v += __shfl_xor(v, 2);
            v += __shfl_xor(v, 4);
            v += __shfl_xor(v, 8);
            float mnew  = fmaxf(m, v);
            float scale = __expf(m - mnew);
            float wgt   = __expf(v - mnew);
            den = den * scale + wgt;
            #pragma unroll
            for (int j = 0; j < 8; ++j) acc[j] = acc[j] * scale + wgt * xlv[j];
            m = mnew;
        }
        float M = fmaxf(m, __shfl_xor(m, 16));
        M = fmaxf(M, __shfl_xor(M, 32));
        float sc = __expf(m - M);
        float d2 = den * sc;
        d2 += __shfl_xor(d2, 16);
        d2 += __shfl_xor(d2, 32);
        float inv = 1.f / (d2 + 1e-16f);
        float o[8];
        #pragma unroll
        for (int j = 0; j < 8; ++j) {
            float a = acc[j] * sc;
            a += __shfl_xor(a, 16);
            a += __shfl_xor(a, 32);
            float val = a * inv + bv[j];
            o[j] = do_relu ? fmaxf(val, 0.f) : val;
        }
        if (g == 0) {
            *(float4*)&out[((size_t)n << 7) + c0]     = make_float4(o[0], o[1], o[2], o[3]);
            *(float4*)&out[((size_t)n << 7) + c0 + 4] = make_float4(o[4], o[5], o[6], o[7]);
        }
    }
}

// ---------------------------------------------------------------- launch

static inline char* carve(char*& p, size_t bytes) {
    char* r = p;
    p += (bytes + 255) & ~(size_t)255;
    return r;
}

extern "C" void kernel_launch(void* const* d_in, const int* in_sizes, int n_in,
                              void* d_out, int out_size, void* d_ws, size_t ws_size,
                              hipStream_t stream)
{
    const int* edge_index = (const int*)d_in[0];
    int E = in_sizes[0] / 2;
    int N = in_sizes[2] / 128;
    const int* srcv = edge_index;
    const int* dstv = edge_index + E;
    const float* eattr = (const float*)d_in[1];
    const float* x = (const float*)d_in[2];

    char* p = (char*)d_ws;
    int*   deg    = (int*)  carve(p, (size_t)N * 4);
    int*   fill   = (int*)  carve(p, (size_t)N * 4);
    int*   rowptr = (int*)  carve(p, (size_t)(N + 1) * 4);
    int*   col    = (int*)  carve(p, (size_t)(E + N) * 4);
    float* eperm  = (float*)carve(p, (size_t)(E + N) * 16);
    unsigned short* xlh = (unsigned short*)carve(p, (size_t)N * 256);
    float* xrb    = (float*)carve(p, (size_t)N * 512);
    unsigned short* Thi = (unsigned short*)carve(p, (size_t)3 * 256 * 128 * 2);
    unsigned short* Tlo = (unsigned short*)carve(p, (size_t)3 * 256 * 128 * 2);

    hipMemsetAsync(deg,  0, (size_t)N * 4, stream);
    hipMemsetAsync(fill, 0, (size_t)N * 4, stream);

    count_deg_kernel<<<(E + 255) / 256, 256, 0, stream>>>(dstv, deg, E);
    scan_kernel<<<1, 1024, 0, stream>>>(deg, rowptr, N);
    fill_csr_kernel<<<(E + 255) / 256, 256, 0, stream>>>(srcv, dstv, eattr, rowptr, fill, col, eperm, E);
    selfloop_kernel<<<(N + 255) / 256, 256, 0, stream>>>(rowptr, deg, col, eperm, N);

    for (int li = 0; li < 3; ++li) {
        const float* Wl = (const float*)d_in[3 + 5 * li + 0];
        const float* Wr = (const float*)d_in[3 + 5 * li + 1];
        wprep_kernel<<<256, 128, 0, stream>>>(Wl, Wr,
                                              Thi + (size_t)li * 256 * 128,
                                              Tlo + (size_t)li * 256 * 128);
    }

    float* out = (float*)d_out;
    for (int li = 0; li < 3; ++li) {
        const float* Wep = (const float*)d_in[3 + 5 * li + 2];
        const float* atp = (const float*)d_in[3 + 5 * li + 3];
        const float* bp  = (const float*)d_in[3 + 5 * li + 4];
        const float* hin = (li == 0) ? x : out;
        gemm_mfma_kernel<<<(N + 63) / 64, 256, 0, stream>>>(
            hin, Thi + (size_t)li * 256 * 128, Tlo + (size_t)li * 256 * 128, xlh, xrb, N);
        gat_agg_kernel<<<(N + 15) / 16, 256, 0, stream>>>(xlh, xrb, rowptr, col, eperm,
                                                          Wep, atp, bp, out, N, li < 2 ? 1 : 0);
    }
}

// Round 6
// 829.842 us; speedup vs baseline: 2.3490x; 1.0736x over previous
//
#include <hip/hip_runtime.h>
#include <hip/hip_bf16.h>
#include <cmath>

#define SLOPE 0.2f

typedef __attribute__((ext_vector_type(8))) short bf16x8;
typedef __attribute__((ext_vector_type(4))) float f32x4;
typedef __attribute__((ext_vector_type(2))) float f32x2;

union bfpack { bf16x8 v; unsigned int u[4]; };

__device__ __forceinline__ unsigned short bf16_rne(float x) {
    unsigned int b = __float_as_uint(x);
    b += 0x7FFFu + ((b >> 16) & 1u);
    return (unsigned short)(b >> 16);
}
__device__ __forceinline__ float bf16_tof(unsigned short h) {
    return __uint_as_float(((unsigned int)h) << 16);
}
__device__ __forceinline__ f32x2 splat2(float s) { return (f32x2){s, s}; }

// ---------------------------------------------------------------- preprocessing

__global__ __launch_bounds__(256) void count_deg_kernel(
    const int* __restrict__ dstv, int* __restrict__ deg, int E)
{
    int e = blockIdx.x * 256 + threadIdx.x;
    if (e >= E) return;
    atomicAdd(&deg[dstv[e]], 1);
}

// exclusive prefix over (deg[i]+1): rowptr[0]=0, rowptr[i+1]=sum_{j<=i}(deg[j]+1)
__global__ void scan_kernel(const int* __restrict__ deg, int* __restrict__ rowptr, int N)
{
    __shared__ int swsum[16];
    __shared__ int sbase[16];
    __shared__ int stotal;
    __shared__ int scarry;
    int t = threadIdx.x, lane = t & 63, w = t >> 6;
    if (t == 0) { scarry = 0; rowptr[0] = 0; }
    __syncthreads();
    for (int base = 0; base < N; base += 1024) {
        int i = base + t;
        int v = (i < N) ? (deg[i] + 1) : 0;
        #pragma unroll
        for (int off = 1; off < 64; off <<= 1) {
            int u = __shfl_up(v, off);
            if (lane >= off) v += u;
        }
        if (lane == 63) swsum[w] = v;
        __syncthreads();
        if (w == 0 && lane < 16) {
            int xv = swsum[lane];
            int orig = xv;
            #pragma unroll
            for (int off = 1; off < 16; off <<= 1) {
                int u = __shfl_up(xv, off);
                if (lane >= off) xv += u;
            }
            sbase[lane] = xv - orig;
            if (lane == 15) stotal = xv;
        }
        __syncthreads();
        if (i < N) rowptr[i + 1] = scarry + sbase[w] + v;
        __syncthreads();
        if (t == 0) scarry += stotal;
        __syncthreads();
    }
}

__global__ __launch_bounds__(256) void fill_csr_kernel(
    const int* __restrict__ srcv, const int* __restrict__ dstv,
    const float* __restrict__ eattr,
    const int* __restrict__ rowptr, int* __restrict__ fill,
    int* __restrict__ col, float* __restrict__ eattr_perm, int E)
{
    int e = blockIdx.x * 256 + threadIdx.x;
    if (e >= E) return;
    int d = dstv[e];
    int pos = rowptr[d] + atomicAdd(&fill[d], 1);
    col[pos] = srcv[e];
    *(float4*)&eattr_perm[(size_t)pos * 4] = *(const float4*)&eattr[(size_t)e * 4];
}

__global__ __launch_bounds__(256) void selfloop_kernel(
    const int* __restrict__ rowptr, const int* __restrict__ deg,
    int* __restrict__ col, float* __restrict__ eattr_perm, int N)
{
    int n = blockIdx.x * 256 + threadIdx.x;
    if (n >= N) return;
    int e0 = rowptr[n], e1 = rowptr[n + 1];
    float4 s = make_float4(0.f, 0.f, 0.f, 0.f);
    for (int e = e0; e < e1 - 1; ++e) {
        float4 a = *(const float4*)&eattr_perm[(size_t)e * 4];
        s.x += a.x; s.y += a.y; s.z += a.z; s.w += a.w;
    }
    float inv = 1.0f / fmaxf((float)deg[n], 1.0f);
    s.x *= inv; s.y *= inv; s.z *= inv; s.w *= inv;
    int pos = e1 - 1;
    col[pos] = n;
    *(float4*)&eattr_perm[(size_t)pos * 4] = s;
}

// W prep: Thi/Tlo[c][k] = bf16 hi/lo split of W[k][c], c in [0,256) = Wl|Wr.
__global__ __launch_bounds__(128) void wprep_kernel(
    const float* __restrict__ Wl, const float* __restrict__ Wr,
    unsigned short* __restrict__ Thi, unsigned short* __restrict__ Tlo)
{
    int c = blockIdx.x;      // 0..255
    int k = threadIdx.x;     // 0..127
    const float* W = (c < 128) ? Wl : Wr;
    float v = W[(size_t)k * 128 + (c & 127)];
    unsigned short h = bf16_rne(v);
    float lo = v - bf16_tof(h);
    Thi[(size_t)c * 128 + k] = h;
    Tlo[(size_t)c * 128 + k] = bf16_rne(lo);
}

// ---------------------------------------------------------------- MFMA GEMM (bf16x3)
__global__ __launch_bounds__(256, 2) void gemm_mfma_kernel(
    const float* __restrict__ H,
    const unsigned short* __restrict__ Thi, const unsigned short* __restrict__ Tlo,
    unsigned short* __restrict__ XLH, float* __restrict__ XR, int nrows)
{
    __shared__ unsigned short sHi[64 * 128];
    __shared__ unsigned short sLo[64 * 128];
    int t = threadIdx.x;
    int r0 = blockIdx.x * 64;

    #pragma unroll
    for (int i = 0; i < 4; ++i) {
        int row = i * 16 + (t >> 4);
        int chunk = t & 15;
        int gr = min(r0 + row, nrows - 1);
        float4 a = *(const float4*)&H[(size_t)gr * 128 + chunk * 8];
        float4 b = *(const float4*)&H[(size_t)gr * 128 + chunk * 8 + 4];
        float v[8] = {a.x, a.y, a.z, a.w, b.x, b.y, b.z, b.w};
        union { bf16x8 v; unsigned short u[8]; } hv, lv;
        #pragma unroll
        for (int j = 0; j < 8; ++j) {
            unsigned short h = bf16_rne(v[j]);
            hv.u[j] = h;
            lv.u[j] = bf16_rne(v[j] - bf16_tof(h));
        }
        int slot = chunk ^ (row & 7);
        *(bf16x8*)&sHi[row * 128 + slot * 8] = hv.v;
        *(bf16x8*)&sLo[row * 128 + slot * 8] = lv.v;
    }
    __syncthreads();

    int w  = t >> 6;
    int l  = t & 63;
    int lr = l & 15;
    int lk = l >> 4;
    int cbase = w * 64;

    f32x4 acc[4][4];
    #pragma unroll
    for (int i = 0; i < 4; ++i)
        #pragma unroll
        for (int j = 0; j < 4; ++j)
            acc[i][j] = (f32x4){0.f, 0.f, 0.f, 0.f};

    #pragma unroll
    for (int k0 = 0; k0 < 128; k0 += 32) {
        bf16x8 ah[4], al[4];
        #pragma unroll
        for (int rt = 0; rt < 4; ++rt) {
            int row = rt * 16 + lr;
            int chunk = (k0 >> 3) + lk;
            int slot = chunk ^ (row & 7);
            ah[rt] = *(const bf16x8*)&sHi[row * 128 + slot * 8];
            al[rt] = *(const bf16x8*)&sLo[row * 128 + slot * 8];
        }
        int k = k0 + lk * 8;
        #pragma unroll
        for (int ct = 0; ct < 4; ++ct) {
            int c = cbase + ct * 16 + lr;
            bf16x8 bh = *(const bf16x8*)&Thi[(size_t)c * 128 + k];
            bf16x8 bl = *(const bf16x8*)&Tlo[(size_t)c * 128 + k];
            #pragma unroll
            for (int rt = 0; rt < 4; ++rt) {
                acc[rt][ct] = __builtin_amdgcn_mfma_f32_16x16x32_bf16(ah[rt], bh, acc[rt][ct], 0, 0, 0);
                acc[rt][ct] = __builtin_amdgcn_mfma_f32_16x16x32_bf16(al[rt], bh, acc[rt][ct], 0, 0, 0);
                acc[rt][ct] = __builtin_amdgcn_mfma_f32_16x16x32_bf16(ah[rt], bl, acc[rt][ct], 0, 0, 0);
            }
        }
    }

    int ccol0 = (cbase & 127);
    if (w < 2) {
        #pragma unroll
        for (int rt = 0; rt < 4; ++rt)
            #pragma unroll
            for (int ct = 0; ct < 4; ++ct) {
                int cc = ccol0 + ct * 16 + lr;
                #pragma unroll
                for (int q = 0; q < 4; ++q) {
                    int r = r0 + rt * 16 + lk * 4 + q;
                    if (r < nrows) XLH[(size_t)r * 128 + cc] = bf16_rne(acc[rt][ct][q]);
                }
            }
    } else {
        #pragma unroll
        for (int rt = 0; rt < 4; ++rt)
            #pragma unroll
            for (int ct = 0; ct < 4; ++ct) {
                int cc = ccol0 + ct * 16 + lr;
                #pragma unroll
                for (int q = 0; q < 4; ++q) {
                    int r = r0 + rt * 16 + lk * 4 + q;
                    if (r < nrows) XR[(size_t)r * 128 + cc] = acc[rt][ct][q];
                }
            }
    }
}

// ---------------------------------------------------------------- fused GATv2 attention + aggregation
// wave = 4 consecutive nodes; per node 4 edges in flight (16 lanes/edge, 8 ch/lane);
// packed-f32 (v_pk_*) channel math, defer-max online softmax, 1-deep edge prefetch.
__global__ __launch_bounds__(256) void gat_agg_kernel(
    const unsigned short* __restrict__ xlh, const float* __restrict__ xr,
    const int* __restrict__ rowptr, const int* __restrict__ col,
    const float* __restrict__ eattr_perm,
    const float* __restrict__ We, const float* __restrict__ att, const float* __restrict__ bias,
    float* __restrict__ out, int N, int do_relu)
{
    int w = threadIdx.x >> 6;
    int lane = threadIdx.x & 63;
    int g = lane >> 4;
    int lg = lane & 15;
    int c0 = lg * 8;

    f32x2 at2[4], we2[4][4];
    float bv[8];
    #pragma unroll
    for (int p = 0; p < 4; ++p) at2[p] = (f32x2){att[c0 + 2 * p], att[c0 + 2 * p + 1]};
    #pragma unroll
    for (int j = 0; j < 8; ++j) bv[j] = bias[c0 + j];
    #pragma unroll
    for (int k = 0; k < 4; ++k)
        #pragma unroll
        for (int p = 0; p < 4; ++p)
            we2[k][p] = (f32x2){We[k * 128 + c0 + 2 * p], We[k * 128 + c0 + 2 * p + 1]};

    int nbase = (blockIdx.x * 4 + w) * 4;
    for (int i = 0; i < 4; ++i) {
        int n = nbase + i;
        if (n >= N) return;           // wave-uniform

        f32x2 xr2[4];
        {
            float4 a = *(const float4*)&xr[((size_t)n << 7) + c0];
            float4 b = *(const float4*)&xr[((size_t)n << 7) + c0 + 4];
            xr2[0] = (f32x2){a.x, a.y}; xr2[1] = (f32x2){a.z, a.w};
            xr2[2] = (f32x2){b.x, b.y}; xr2[3] = (f32x2){b.z, b.w};
        }

        int e0 = rowptr[n], e1 = rowptr[n + 1];
        float m = -INFINITY, den = 0.f;
        f32x2 acc2[4];
        #pragma unroll
        for (int p = 0; p < 4; ++p) acc2[p] = (f32x2){0.f, 0.f};

        int e = e0 + g;
        // prefetch first edge
        float4 eavN = make_float4(0.f, 0.f, 0.f, 0.f);
        bfpack xvN;
        xvN.u[0] = xvN.u[1] = xvN.u[2] = xvN.u[3] = 0;
        if (e < e1) {
            int s = col[e];
            eavN = *(const float4*)&eattr_perm[(size_t)e * 4];
            xvN.v = *(const bf16x8*)&xlh[((size_t)(unsigned)s << 7) + c0];
        }

        while (e < e1) {
            float4 eav = eavN;
            bfpack xv = xvN;
            int en = e + 4;
            if (en < e1) {
                int s2 = col[en];
                eavN = *(const float4*)&eattr_perm[(size_t)en * 4];
                xvN.v = *(const bf16x8*)&xlh[((size_t)(unsigned)s2 << 7) + c0];
            }

            // decode bf16 pairs -> f32x2 (lo = bits<<16, hi = bits&0xffff0000)
            f32x2 xl2[4];
            #pragma unroll
            for (int p = 0; p < 4; ++p) {
                unsigned int u = xv.u[p];
                xl2[p] = (f32x2){__uint_as_float(u << 16), __uint_as_float(u & 0xffff0000u)};
            }
            f32x2 vd = (f32x2){0.f, 0.f};
            #pragma unroll
            for (int p = 0; p < 4; ++p) {
                f32x2 z = xl2[p] + xr2[p];
                z += splat2(eav.x) * we2[0][p];
                z += splat2(eav.y) * we2[1][p];
                z += splat2(eav.z) * we2[2][p];
                z += splat2(eav.w) * we2[3][p];
                f32x2 zs = splat2(SLOPE) * z;
                f32x2 lz = (f32x2){fmaxf(z.x, zs.x), fmaxf(z.y, zs.y)};
                vd += lz * at2[p];
            }
            float v = vd.x + vd.y;
            v += __shfl_xor(v, 1);
            v += __shfl_xor(v, 2);
            v += __shfl_xor(v, 4);
            v += __shfl_xor(v, 8);

            if (v - m > 8.0f) {          // rare: new max grew past threshold
                float scale = __expf(m - v);     // 0 on first edge (m=-inf)
                den = den * scale + 1.0f;
                #pragma unroll
                for (int p = 0; p < 4; ++p) acc2[p] = acc2[p] * splat2(scale) + xl2[p];
                m = v;
            } else {                     // common: no rescale (P bounded by e^8)
                float wgt = __expf(v - m);
                den += wgt;
                #pragma unroll
                for (int p = 0; p < 4; ++p) acc2[p] += splat2(wgt) * xl2[p];
            }
            e = en;
        }

        // combine 4 groups (differing running maxima)
        float M = fmaxf(m, __shfl_xor(m, 16));
        M = fmaxf(M, __shfl_xor(M, 32));
        float sc = __expf(m - M);        // 0 for empty groups
        float d2 = den * sc;
        d2 += __shfl_xor(d2, 16);
        d2 += __shfl_xor(d2, 32);
        float inv = 1.f / (d2 + 1e-16f);
        float o[8];
        #pragma unroll
        for (int p = 0; p < 4; ++p) {
            float ax = acc2[p].x * sc;
            float ay = acc2[p].y * sc;
            ax += __shfl_xor(ax, 16); ax += __shfl_xor(ax, 32);
            ay += __shfl_xor(ay, 16); ay += __shfl_xor(ay, 32);
            float vx = ax * inv + bv[2 * p];
            float vy = ay * inv + bv[2 * p + 1];
            o[2 * p]     = do_relu ? fmaxf(vx, 0.f) : vx;
            o[2 * p + 1] = do_relu ? fmaxf(vy, 0.f) : vy;
        }
        if (g == 0) {
            *(float4*)&out[((size_t)n << 7) + c0]     = make_float4(o[0], o[1], o[2], o[3]);
            *(float4*)&out[((size_t)n << 7) + c0 + 4] = make_float4(o[4], o[5], o[6], o[7]);
        }
    }
}

// ---------------------------------------------------------------- launch

static inline char* carve(char*& p, size_t bytes) {
    char* r = p;
    p += (bytes + 255) & ~(size_t)255;
    return r;
}

extern "C" void kernel_launch(void* const* d_in, const int* in_sizes, int n_in,
                              void* d_out, int out_size, void* d_ws, size_t ws_size,
                              hipStream_t stream)
{
    const int* edge_index = (const int*)d_in[0];
    int E = in_sizes[0] / 2;
    int N = in_sizes[2] / 128;
    const int* srcv = edge_index;
    const int* dstv = edge_index + E;
    const float* eattr = (const float*)d_in[1];
    const float* x = (const float*)d_in[2];

    char* p = (char*)d_ws;
    int*   deg    = (int*)  carve(p, (size_t)N * 4);
    int*   fill   = (int*)  carve(p, (size_t)N * 4);
    int*   rowptr = (int*)  carve(p, (size_t)(N + 1) * 4);
    int*   col    = (int*)  carve(p, (size_t)(E + N) * 4);
    float* eperm  = (float*)carve(p, (size_t)(E + N) * 16);
    unsigned short* xlh = (unsigned short*)carve(p, (size_t)N * 256);
    float* xrb    = (float*)carve(p, (size_t)N * 512);
    unsigned short* Thi = (unsigned short*)carve(p, (size_t)3 * 256 * 128 * 2);
    unsigned short* Tlo = (unsigned short*)carve(p, (size_t)3 * 256 * 128 * 2);

    hipMemsetAsync(deg,  0, (size_t)N * 4, stream);
    hipMemsetAsync(fill, 0, (size_t)N * 4, stream);

    count_deg_kernel<<<(E + 255) / 256, 256, 0, stream>>>(dstv, deg, E);
    scan_kernel<<<1, 1024, 0, stream>>>(deg, rowptr, N);
    fill_csr_kernel<<<(E + 255) / 256, 256, 0, stream>>>(srcv, dstv, eattr, rowptr, fill, col, eperm, E);
    selfloop_kernel<<<(N + 255) / 256, 256, 0, stream>>>(rowptr, deg, col, eperm, N);

    for (int li = 0; li < 3; ++li) {
        const float* Wl = (const float*)d_in[3 + 5 * li + 0];
        const float* Wr = (const float*)d_in[3 + 5 * li + 1];
        wprep_kernel<<<256, 128, 0, stream>>>(Wl, Wr,
                                              Thi + (size_t)li * 256 * 128,
                                              Tlo + (size_t)li * 256 * 128);
    }

    float* out = (float*)d_out;
    for (int li = 0; li < 3; ++li) {
        const float* Wep = (const float*)d_in[3 + 5 * li + 2];
        const float* atp = (const float*)d_in[3 + 5 * li + 3];
        const float* bp  = (const float*)d_in[3 + 5 * li + 4];
        const float* hin = (li == 0) ? x : out;
        gemm_mfma_kernel<<<(N + 63) / 64, 256, 0, stream>>>(
            hin, Thi + (size_t)li * 256 * 128, Tlo + (size_t)li * 256 * 128, xlh, xrb, N);
        gat_agg_kernel<<<(N + 15) / 16, 256, 0, stream>>>(xlh, xrb, rowptr, col, eperm,
                                                          Wep, atp, bp, out, N, li < 2 ? 1 : 0);
    }
}